// Round 1
// baseline (53.160 us; speedup 1.0000x reference)
//
#include <hip/hip_runtime.h>

typedef float  f32x16 __attribute__((ext_vector_type(16)));
typedef __bf16 bf16x8 __attribute__((ext_vector_type(8)));
typedef short  short8 __attribute__((ext_vector_type(8)));

#define F      65
#define NT     9            // 8 D-tiles of 32 cols + 1 S-tile (cols 256..287, 8 real)
#define KS     5            // K padded 65 -> 80, 5 ksteps of 16
#define RPB    128          // rows per block (4 waves x 32)
#define NCHUNK (NT*KS*64)   // 2880 16B chunks in W blob (46080 B)

__device__ __forceinline__ unsigned short f2bf(float f) {
  unsigned int u = __builtin_bit_cast(unsigned int, f);
  u += 0x7FFFu + ((u >> 16) & 1u);          // RNE
  return (unsigned short)(u >> 16);
}
__device__ __forceinline__ float bf2f(unsigned short h) {
  return __builtin_bit_cast(float, ((unsigned int)h) << 16);
}
__device__ __forceinline__ float fast_sigmoid(float x) {
  float e = __builtin_amdgcn_exp2f(-1.4426950408889634f * x);
  return __builtin_amdgcn_rcpf(1.0f + e);
}
template<int CTRL>
__device__ __forceinline__ float dpp_mov(float v) {
  return __builtin_bit_cast(float,
    __builtin_amdgcn_update_dpp(0, __builtin_bit_cast(int, v), CTRL, 0xF, 0xF, true));
}

// ---- prepass: build fragment-ordered bf16 W blob in d_ws -------------------
// blob chunk index = (t*KS+s)*64 + lane ; 8 bf16 per lane:
//   n = 32*t + (lane&31), k = 16*s + 4*(lane>>5) + (j&3) + 8*(j>>2)
__global__ void prep_w(const float* __restrict__ W_S, const float* __restrict__ W_D,
                       unsigned short* __restrict__ wsb) {
  int b = blockIdx.x;              // 0..44 = t*KS+s
  int t = b / KS, s = b % KS;
  int l = threadIdx.x;             // 0..63
  int c = l & 31, g = l >> 5;
  short8 out;
#pragma unroll
  for (int j = 0; j < 8; ++j) {
    int k = 16 * s + 4 * g + (j & 3) + 8 * (j >> 2);
    int n = 32 * t + c;
    float v = 0.0f;
    if (k < F) {
      if (t < 8)      v = W_D[n * F + k];
      else if (c < 8) v = W_S[c * F + k];
    }
    out[j] = (short)f2bf(v);
  }
  reinterpret_cast<short8*>(wsb)[b * 64 + l] = out;
}

// ---- main fused kernel -----------------------------------------------------
__launch_bounds__(256, 2)
__global__ void mpuf_main(const float* __restrict__ phi,
                          const float* __restrict__ b_S,
                          const float* __restrict__ b_D,
                          const unsigned short* __restrict__ wsb,
                          float* __restrict__ out_ans,
                          float* __restrict__ out_rel) {
  __shared__ short8 ldsB[NCHUNK];          // 46080 B
  __shared__ short8 soutv[4 * 32];         // Souts bf16 [wave*32+row][8], 2048 B

  const int tid  = threadIdx.x;
  const int wave = tid >> 6;
  const int l    = tid & 63;
  const int c    = l & 31;                 // A-row within rowblock / B-col within tile
  const int g    = l >> 5;

  // stage W blob -> LDS (coalesced 16B chunks)
  const short8* wsv = reinterpret_cast<const short8*>(wsb);
#pragma unroll
  for (int i = 0; i < 12; ++i) {
    int idx = tid + i * 256;
    if (idx < NCHUNK) ldsB[idx] = wsv[idx];
  }

  float bD[8];
#pragma unroll
  for (int t = 0; t < 8; ++t) bD[t] = b_D[32 * t + c];
  const float bS = b_S[c & 7];             // only meaningful when c<8

  const int rowg_base = blockIdx.x * RPB + wave * 32;
  const float* prow = phi + (long)(rowg_base + c) * F;

  // issue ALL A loads up-front (33 dwords/lane in flight -> latency hidden)
  float aL[4][8];
#pragma unroll
  for (int s = 0; s < 4; ++s)
#pragma unroll
    for (int j = 0; j < 8; ++j)
      aL[s][j] = prow[16 * s + 4 * g + (j & 3) + 8 * (j >> 2)];
  const float a64 = prow[64];

  __syncthreads();

  f32x16 acc[NT] = {};

#pragma unroll
  for (int s = 0; s < KS; ++s) {
    short8 araw;
    if (s < 4) {
#pragma unroll
      for (int j = 0; j < 8; ++j) araw[j] = (short)f2bf(aL[s][j]);
    } else {                                // kstep 4: only k==64 real (g==0, j==0)
#pragma unroll
      for (int j = 0; j < 8; ++j) araw[j] = 0;
      if (g == 0) araw[0] = (short)f2bf(a64);
    }
    bf16x8 af = __builtin_bit_cast(bf16x8, araw);
#pragma unroll
    for (int t = 0; t < NT; ++t) {
      bf16x8 bf = __builtin_bit_cast(bf16x8, ldsB[(t * KS + s) * 64 + l]);
      acc[t] = __builtin_amdgcn_mfma_f32_32x32x16_bf16(af, bf, acc[t], 0, 0, 0);
    }
  }

  // ---- epilogue: S-tile first (tile 8, cols 256..263 hold Sdelta) ----------
  // C layout (verified): col = lane&31, row = (r&3) + 8*(r>>2) + 4*(lane>>5)
  if (c < 8) {
#pragma unroll
    for (int r = 0; r < 16; ++r) {
      int rl = (r & 3) + 8 * (r >> 2) + 4 * g;
      float sd = acc[8][r] + bS;
      out_rel[(rowg_base + rl) * 8 + c] = fabsf(sd);
      reinterpret_cast<unsigned short*>(&soutv[wave * 32 + rl])[c] =
          f2bf(fast_sigmoid(sd));
    }
  }
  __syncthreads();

  // ---- per-row: M products + sigmoid + gated row-sum -----------------------
#pragma unroll
  for (int r = 0; r < 16; ++r) {
    int rl = (r & 3) + 8 * (r >> 2) + 4 * g;
    short8 sraw = soutv[wave * 32 + rl];   // broadcast read, conflict-free
    float sv[8], ov[8];
#pragma unroll
    for (int i = 0; i < 8; ++i) {
      sv[i] = bf2f((unsigned short)sraw[i]);
      ov[i] = 1.0f - sv[i];
    }
    // M[d] = prod_i (bit_i(d) ? s_i : 1-s_i); d = 32*t + c
    float Mlane = 0.99999f;
#pragma unroll
    for (int i = 0; i < 5; ++i) Mlane *= ((c >> i) & 1) ? sv[i] : ov[i];
    float a67[4] = { ov[6] * ov[7], sv[6] * ov[7], ov[6] * sv[7], sv[6] * sv[7] };
    float acc_ans = 0.0f;
#pragma unroll
    for (int t = 0; t < 8; ++t) {
      float Mt = ((t & 1) ? sv[5] : ov[5]) * a67[t >> 1];
      float x  = acc[t][r] + bD[t];
      float dout = fast_sigmoid(x);
      acc_ans += dout * (Mlane * Mt);
    }
    // reduce over the 32 lanes sharing this row: 4 DPP steps + xor16 swizzle
    float v = acc_ans;
    v += dpp_mov<0xB1>(v);                 // quad_perm xor1
    v += dpp_mov<0x4E>(v);                 // quad_perm xor2
    v += dpp_mov<0x141>(v);                // row_half_mirror (xor4-equiv)
    v += dpp_mov<0x140>(v);                // row_mirror (xor8-equiv)
    v += __builtin_bit_cast(float,
          __builtin_amdgcn_ds_swizzle(__builtin_bit_cast(int, v), 0x401F)); // xor16
    if (c == 0) out_ans[rowg_base + rl] = v;
  }
}

extern "C" void kernel_launch(void* const* d_in, const int* in_sizes, int n_in,
                              void* d_out, int out_size, void* d_ws, size_t ws_size,
                              hipStream_t stream) {
  const float* phi = (const float*)d_in[0];
  const float* W_S = (const float*)d_in[1];
  const float* b_S = (const float*)d_in[2];
  const float* W_D = (const float*)d_in[3];
  const float* b_D = (const float*)d_in[4];
  // d_in[5]/d_in[6] (Wmat/Bmat) are pure bit-selects -> unused
  const int rows = in_sizes[0] / F;        // 262144
  unsigned short* wsb = (unsigned short*)d_ws;   // 46080 B used
  float* out_ans = (float*)d_out;
  float* out_rel = out_ans + rows;
  hipLaunchKernelGGL(prep_w, dim3(NT * KS), dim3(64), 0, stream, W_S, W_D, wsb);
  hipLaunchKernelGGL(mpuf_main, dim3(rows / RPB), dim3(256), 0, stream,
                     phi, b_S, b_D, wsb, out_ans, out_rel);
}